// Round 1
// baseline (1133.158 us; speedup 1.0000x reference)
//
#include <hip/hip_runtime.h>
#include <cstdint>
#include <cmath>

// TropicalHashGrid forward, R4.
// R2: level-major dispatch -> gathers are L2-hits; bound ~2.5 cyc/gather-lane.
// R3: pair-packing cut lookups 268M -> ~180M (hashed 8->6 avg, dense 8->4).
// R4 theory: part of the 2.5 cyc/lane is L1 allocate/refill churn (tables
// 0.5-4 MiB >> 32 KiB L1, hit rate ~0 on big levels; every gather miss drags
// a 64B line through L1). Fix: sc0 (agent-coherent) gathers bypass L1
// allocation and read straight from the XCD L2 where the table lives.
//  - hashed levels (4 MiB tables): always sc0
//  - dense levels: sc0 when repacked table > 256 KiB (l2..l4); l0/l1 keep L1
// Inline-asm loads are invisible to compiler vmcnt bookkeeping, so each
// gather batch ends with one s_waitcnt vmcnt(0) asm whose operands tie the
// loaded values ("+v") -- uses cannot be hoisted above the wait.

typedef float f32x2 __attribute__((ext_vector_type(2)));
typedef float f32x4 __attribute__((ext_vector_type(4)));

#define NLEVELS 16
#define HASHMAP (1 << 19)
#define HMASK ((uint32_t)(HASHMAP - 1))
#define PRIME_Y 2654435761u
#define PRIME_Z 805459861u

struct HGParams {
    float scale[NLEVELS];
    int   res[NLEVELS];
    int   dense[NLEVELS];
    int   dpk_off[NLEVELS];  // float4 offset of repacked dense table, or -1
    int   bypass[NLEVELS];   // 1 = use sc0 (L1-bypass) gathers
};

// L1-bypassing gathers. sc0 on gfx950 = agent-coherent load (no L1 allocate).
__device__ __forceinline__ f32x4 gload4_sc0(const f32x4* p) {
    f32x4 v;
    asm volatile("global_load_dwordx4 %0, %1, off sc0" : "=&v"(v) : "v"(p));
    return v;
}
__device__ __forceinline__ f32x2 gload2_sc0(const f32x2* p) {
    f32x2 v;
    asm volatile("global_load_dwordx2 %0, %1, off sc0" : "=&v"(v) : "v"(p));
    return v;
}

// Overlapping-pair repack of dense tables: dpk[k] = (tbl[k], tbl[k+1]).
// Reading tbl[res^3] is safe: each level owns HASHMAP entries > res^3.
__global__ __launch_bounds__(256) void repack_dense_k(
    const f32x2* __restrict__ table, f32x4* __restrict__ dpk, HGParams p)
{
    const int l = blockIdx.y;
    if (!p.dense[l] || p.dpk_off[l] < 0) return;
    const int res = p.res[l];
    const int res3 = res * res * res;
    const f32x2* __restrict__ src = table + (size_t)l * HASHMAP;
    f32x4* __restrict__ dst = dpk + p.dpk_off[l];
    for (int k = blockIdx.x * 256 + threadIdx.x; k < res3; k += gridDim.x * 256) {
        const f32x2 a = src[k];
        const f32x2 b = src[k + 1];
        f32x4 v; v.x = a.x; v.y = a.y; v.z = b.x; v.w = b.y;
        dst[k] = v;
    }
}

// One block = 256 points x 1 level (level = blockIdx.y, slowest dim -> one
// level's 4 MiB table hot per XCD L2).
// dst[l*stride_l + n*stride_n]: ws path stride_l=N,stride_n=1; direct path
// stride_l=1,stride_n=16.
__global__ __launch_bounds__(256) void hashgrid_level(
    const float* __restrict__ x,
    const float* __restrict__ table,
    const f32x4* __restrict__ dpk,   // repacked dense tables or nullptr
    f32x2* __restrict__ dst,
    HGParams p,
    int npoints,
    size_t stride_l,
    size_t stride_n)
{
    __shared__ float sx[768];
    const int tid = threadIdx.x;
    const int base = blockIdx.x << 8;
    const int l = blockIdx.y;

    const int total = npoints * 3;
#pragma unroll
    for (int k = 0; k < 3; ++k) {
        const int li = tid + (k << 8);
        const int gi = base * 3 + li;
        sx[li] = (gi < total) ? x[gi] : 0.0f;
    }
    __syncthreads();

    const int n = base + tid;
    if (n >= npoints) return;

    const float scale = p.scale[l];
    const int   res   = p.res[l];
    const bool  dense = (p.dense[l] != 0);

    const float px = sx[tid * 3 + 0] * scale + 0.5f;
    const float py = sx[tid * 3 + 1] * scale + 0.5f;
    const float pz = sx[tid * 3 + 2] * scale + 0.5f;
    const float fx = floorf(px), fy = floorf(py), fz = floorf(pz);
    const float rx = px - fx,  ry = py - fy,  rz = pz - fz;
    const int ix = (int)fx, iy = (int)fy, iz = (int)fz;

    const f32x2* __restrict__ tbl =
        (const f32x2*)table + (size_t)l * (size_t)HASHMAP;

    const float wx0 = 1.0f - rx, wx1 = rx;
    const float wy_[2] = {1.0f - ry, ry};
    const float wz_[2] = {1.0f - rz, rz};

    float ax = 0.0f, ay = 0.0f;

    if (dense) {
        const int rm = res - 1;
        const int x0 = min(ix, rm), x1 = min(ix + 1, rm);
        const int y0 = min(iy, rm), y1 = min(iy + 1, rm);
        const int z0 = min(iz, rm), z1 = min(iz + 1, rm);
        const int r2 = res * res;
        const int ys[2] = {y0 * res, y1 * res};
        const int zs[2] = {z0 * r2,  z1 * r2};
        const int d = x1 - x0;  // 0 or 1
        if (dpk && p.dpk_off[l] >= 0) {
            const f32x4* __restrict__ dt = dpk + p.dpk_off[l];
            f32x4 f4[4];
            if (p.bypass[l]) {
#pragma unroll
                for (int c = 0; c < 4; ++c)
                    f4[c] = gload4_sc0(dt + x0 + ys[(c >> 1) & 1] + zs[c & 1]);
                asm volatile("s_waitcnt vmcnt(0)"
                             : "+v"(f4[0]), "+v"(f4[1]), "+v"(f4[2]), "+v"(f4[3]));
            } else {
#pragma unroll
                for (int c = 0; c < 4; ++c)
                    f4[c] = dt[x0 + ys[(c >> 1) & 1] + zs[c & 1]];
            }
#pragma unroll
            for (int c = 0; c < 4; ++c) {
                const f32x2 c0 = f4[c].xy;
                const f32x2 c1 = d ? f4[c].zw : f4[c].xy;
                const float wyz = wy_[(c >> 1) & 1] * wz_[c & 1];
                ax += wyz * (wx0 * c0.x + wx1 * c1.x);
                ay += wyz * (wx0 * c0.y + wx1 * c1.y);
            }
        } else {
            f32x2 f0[4], f1[4];
#pragma unroll
            for (int c = 0; c < 4; ++c) {
                const int b = ys[(c >> 1) & 1] + zs[c & 1];
                f0[c] = tbl[x0 + b];
                f1[c] = tbl[x1 + b];
            }
#pragma unroll
            for (int c = 0; c < 4; ++c) {
                const float wyz = wy_[(c >> 1) & 1] * wz_[c & 1];
                ax += wyz * (wx0 * f0[c].x + wx1 * f1[c].x);
                ay += wyz * (wx0 * f0[c].y + wx1 * f1[c].y);
            }
        }
    } else {
        const uint32_t ux = (uint32_t)ix;
        const uint32_t hy[2] = {(uint32_t)iy * PRIME_Y, (uint32_t)(iy + 1) * PRIME_Y};
        const uint32_t hz[2] = {(uint32_t)iz * PRIME_Z, (uint32_t)(iz + 1) * PRIME_Z};
        const f32x4* __restrict__ t4 = (const f32x4*)tbl;

        uint32_t H0[4], H1[4];
#pragma unroll
        for (int c = 0; c < 4; ++c) {
            const uint32_t hyz = hy[(c >> 1) & 1] ^ hz[c & 1];
            H0[c] = (ux ^ hyz) & HMASK;
            H1[c] = ((ux + 1u) ^ hyz) & HMASK;
        }
        // Both x-corners live in one aligned float4 when ix is even:
        // H1 = H0 ^ 1. Load the pair-float4 always (covers corner x0 and,
        // for even lanes, corner x1); odd lanes fetch corner x1 separately.
        // All loads issued first (sc0, L1-bypass), then one tied waitcnt.
        f32x4 f4[4];
#pragma unroll
        for (int c = 0; c < 4; ++c) f4[c] = gload4_sc0(t4 + (H0[c] >> 1));

        f32x2 o[4];
#pragma unroll
        for (int c = 0; c < 4; ++c) { o[c].x = 0.0f; o[c].y = 0.0f; }
        const bool odd = (ux & 1u) != 0u;
        if (odd) {
#pragma unroll
            for (int c = 0; c < 4; ++c) o[c] = gload2_sc0(tbl + H1[c]);
        }
        asm volatile("s_waitcnt vmcnt(0)"
                     : "+v"(f4[0]), "+v"(f4[1]), "+v"(f4[2]), "+v"(f4[3]),
                       "+v"(o[0]), "+v"(o[1]), "+v"(o[2]), "+v"(o[3]));

#pragma unroll
        for (int c = 0; c < 4; ++c) {
            const f32x2 c0 = (H0[c] & 1u) ? f4[c].zw : f4[c].xy;
            const f32x2 cw = (H0[c] & 1u) ? f4[c].xy : f4[c].zw;  // opposite slot
            const f32x2 c1 = odd ? o[c] : cw;
            const float wyz = wy_[(c >> 1) & 1] * wz_[c & 1];
            ax += wyz * (wx0 * c0.x + wx1 * c1.x);
            ay += wyz * (wx0 * c0.y + wx1 * c1.y);
        }
    }

    f32x2 acc; acc.x = ax; acc.y = ay;
    __builtin_nontemporal_store(acc, dst + (size_t)l * stride_l + (size_t)n * stride_n);
}

// Transpose [16][N] f32x2 -> [N][16] f32x2, float4 on both global sides.
// Block handles 128 points. Requires npoints even (guarded at launch).
__global__ __launch_bounds__(256) void transpose_out(
    const f32x4* __restrict__ ws4,
    f32x4* __restrict__ out4,
    int npoints)
{
    __shared__ f32x2 tile[NLEVELS][130];  // stride 130: staggers banks
    const int tid = threadIdx.x;
    const int base = blockIdx.x << 7;    // 128 points per block
    const int np2 = npoints >> 1;        // ws row length in float4

    // Load: wave covers one level, 64 consecutive float4 -> 1 KiB contig.
#pragma unroll
    for (int k = 0; k < 4; ++k) {
        const int flat = tid + (k << 8);
        const int l  = flat >> 6;        // 0..15
        const int pr = flat & 63;        // float4 (point-pair) within tile
        const int gp = (base >> 1) + pr;
        if (gp < np2) {
            const f32x4 v = __builtin_nontemporal_load(ws4 + (size_t)l * np2 + gp);
            tile[l][2 * pr]     = v.xy;
            tile[l][2 * pr + 1] = v.zw;
        }
    }
    __syncthreads();

    // Store: out row per point = 8 float4; fully coalesced.
#pragma unroll
    for (int k = 0; k < 4; ++k) {
        const int flat = tid + (k << 8);
        const int nl = flat >> 3;        // local point 0..127
        const int c  = flat & 7;         // level pair 0..7
        const int nn = base + nl;
        if (nn < npoints) {
            const f32x2 a = tile[2 * c][nl];
            const f32x2 b = tile[2 * c + 1][nl];
            f32x4 v; v.x = a.x; v.y = a.y; v.z = b.x; v.w = b.y;
            __builtin_nontemporal_store(v, out4 + (size_t)nn * 8 + c);
        }
    }
}

extern "C" void kernel_launch(void* const* d_in, const int* in_sizes, int n_in,
                              void* d_out, int out_size, void* d_ws, size_t ws_size,
                              hipStream_t stream) {
    const float* x     = (const float*)d_in[0];
    const float* table = (const float*)d_in[1];
    float* out         = (float*)d_out;
    const int npoints  = in_sizes[0] / 3;

    // Level constants in double, bit-matching the numpy reference.
    HGParams p;
    const double B = pow(2.0, 7.0 / 15.0);
    int dpk_total = 0;   // float4 entries needed for dense repack
    int max_res3 = 0;
    for (int l = 0; l < NLEVELS; ++l) {
        const double s = 16.0 * pow(B, (double)l) - 1.0;
        p.scale[l] = (float)s;
        const int res = (int)ceil(s) + 1;
        p.res[l] = res;
        const long long r3 = (long long)res * res * res;
        p.dense[l] = (r3 <= (long long)HASHMAP) ? 1 : 0;
        if (p.dense[l]) {
            p.dpk_off[l] = dpk_total;
            dpk_total += (int)r3;
            if ((int)r3 > max_res3) max_res3 = (int)r3;
            // L1-bypass only when the repacked table clearly exceeds L1 reach.
            p.bypass[l] = (r3 * 16 > (256 << 10)) ? 1 : 0;
        } else {
            p.dpk_off[l] = -1;
            p.bypass[l] = 1;   // hashed tables are 4 MiB: always bypass
        }
    }

    const size_t need_main = (size_t)npoints * NLEVELS * sizeof(f32x2);
    const size_t need_dpk  = (size_t)dpk_total * sizeof(f32x4);

    const bool ws_main = (ws_size >= need_main) && ((npoints & 1) == 0);
    size_t dpk_byte_off = ws_main ? need_main : 0;
    const bool use_dpk = (ws_size >= dpk_byte_off + need_dpk) && dpk_total > 0;

    f32x4* dpk = use_dpk ? (f32x4*)((char*)d_ws + dpk_byte_off) : nullptr;
    if (use_dpk) {
        const dim3 gr((max_res3 + 255) / 256, NLEVELS);
        repack_dense_k<<<gr, 256, 0, stream>>>((const f32x2*)table, dpk, p);
    }

    const dim3 g1((npoints + 255) / 256, NLEVELS);
    if (ws_main) {
        hashgrid_level<<<g1, 256, 0, stream>>>(
            x, table, dpk, (f32x2*)d_ws, p, npoints, (size_t)npoints, (size_t)1);
        const int nb2 = (npoints + 127) / 128;
        transpose_out<<<nb2, 256, 0, stream>>>(
            (const f32x4*)d_ws, (f32x4*)out, npoints);
    } else {
        hashgrid_level<<<g1, 256, 0, stream>>>(
            x, table, dpk, (f32x2*)out, p, npoints, (size_t)1, (size_t)NLEVELS);
    }
}

// Round 3
// 929.341 us; speedup vs baseline: 1.2193x; 1.2193x over previous
//
#include <hip/hip_runtime.h>
#include <cstdint>
#include <cmath>

// TropicalHashGrid forward, R5 (resubmit: R2 bench lost to GPU timeout).
// R2: level-major dispatch -> gathers are L2-hits.
// R3: pair-packing cut lane-requests 268M -> 180M.
// R4: sc0 L1-bypass NEUTRAL -> bound is vector-memory REQUEST RATE
//     (~2.8 cyc per divergent lane-request; VALU 15%, HBM 15%, occ 92%).
// R5: fewer requests via fp16 tables (scaled x1024 to dodge fp16 denormals,
//     unscaled at output; adds <=~1.5e-7 abs error):
//  - hashed: 4B entries -> aligned 16B quad covers entries h&~3..h|3.
//    x-prime==1 => both x-corners in ONE quad unless ix%4==3 (25%).
//    6 -> 5 avg requests/point/level.
//  - dense: overlapping 2x2 xy-quad repack (clamps baked) -> one 16B
//    request per z-corner: 4 -> 2 requests/point/level.
//  Total 86 -> 65 lane-requests/point (-24%).

typedef float    f32x2 __attribute__((ext_vector_type(2)));
typedef float    f32x4 __attribute__((ext_vector_type(4)));
typedef uint32_t u32x2 __attribute__((ext_vector_type(2)));
typedef uint32_t u32x4 __attribute__((ext_vector_type(4)));
typedef _Float16 h16x2 __attribute__((ext_vector_type(2)));

#define NLEVELS 16
#define HASHMAP (1 << 19)
#define HMASK ((uint32_t)(HASHMAP - 1))
#define PRIME_Y 2654435761u
#define PRIME_Z 805459861u
#define F16SCALE 1024.0f
#define F16UNSCALE (1.0f / 1024.0f)

struct HGParams {
    float scale[NLEVELS];
    int   res[NLEVELS];
    int   dense[NLEVELS];
    int   dpk_off[NLEVELS];  // tier-B fp32 dense pair repack, f32x4 units, -1 none
    int   hq_off[NLEVELS];   // fp16 hashed table, u32x4 units, -1 none
    int   dq_off[NLEVELS];   // fp16 dense 2x2 quad table, u32x4 units, -1 none
};

__device__ __forceinline__ uint32_t sel4(u32x4 q, uint32_t k) {
    const uint32_t a = (k & 1u) ? q.y : q.x;
    const uint32_t b = (k & 1u) ? q.w : q.z;
    return (k & 2u) ? b : a;
}
__device__ __forceinline__ void unpack_h2(uint32_t w, float& lo, float& hi) {
    const h16x2 h = __builtin_bit_cast(h16x2, w);
    lo = (float)h.x; hi = (float)h.y;
}
__device__ __forceinline__ uint32_t pack_h2(float a, float b) {
    h16x2 h; h.x = (_Float16)a; h.y = (_Float16)b;
    return __builtin_bit_cast(uint32_t, h);
}

// ---- fp16 repack: hashed tables (identity layout, scaled x1024) ----
__global__ __launch_bounds__(256) void repack_hashed_f16(
    const f32x4* __restrict__ table2, uint32_t* __restrict__ hqw, HGParams p)
{
    const int l = blockIdx.y;
    if (p.hq_off[l] < 0) return;
    const f32x4* __restrict__ src = table2 + (size_t)l * (HASHMAP / 2);
    u32x2* __restrict__ dst = (u32x2*)(hqw + (size_t)p.hq_off[l] * 4);
    for (int k = blockIdx.x * 256 + threadIdx.x; k < HASHMAP / 2;
         k += gridDim.x * 256) {
        const f32x4 v = src[k];   // two entries
        u32x2 w;
        w.x = pack_h2(v.x * F16SCALE, v.y * F16SCALE);
        w.y = pack_h2(v.z * F16SCALE, v.w * F16SCALE);
        dst[k] = w;
    }
}

// ---- fp16 repack: dense 2x2 xy-quads, clamps baked in ----
__global__ __launch_bounds__(256) void repack_dense_f16(
    const f32x2* __restrict__ table, u32x4* __restrict__ dqt, HGParams p)
{
    const int l = blockIdx.y;
    if (p.dq_off[l] < 0) return;
    const int res = p.res[l];
    const int rm = res - 1;
    const int r2 = res * res;
    const int res3 = r2 * res;
    const f32x2* __restrict__ src = table + (size_t)l * HASHMAP;
    u32x4* __restrict__ dst = dqt + p.dq_off[l];
    for (int k = blockIdx.x * 256 + threadIdx.x; k < res3;
         k += gridDim.x * 256) {
        const int x = k % res;
        const int t = k / res;
        const int y = t % res;
        const int dx = (x < rm) ? 1 : 0;
        const int dy = (y < rm) ? res : 0;
        const f32x2 e00 = src[k];
        const f32x2 e10 = src[k + dx];
        const f32x2 e01 = src[k + dy];
        const f32x2 e11 = src[k + dx + dy];
        u32x4 w;
        w.x = pack_h2(e00.x * F16SCALE, e00.y * F16SCALE);
        w.y = pack_h2(e10.x * F16SCALE, e10.y * F16SCALE);
        w.z = pack_h2(e01.x * F16SCALE, e01.y * F16SCALE);
        w.w = pack_h2(e11.x * F16SCALE, e11.y * F16SCALE);
        dst[k] = w;
    }
}

// ---- tier-B fp32 dense pair repack (fallback) ----
__global__ __launch_bounds__(256) void repack_dense_k(
    const f32x2* __restrict__ table, f32x4* __restrict__ dpk, HGParams p)
{
    const int l = blockIdx.y;
    if (!p.dense[l] || p.dpk_off[l] < 0) return;
    const int res = p.res[l];
    const int res3 = res * res * res;
    const f32x2* __restrict__ src = table + (size_t)l * HASHMAP;
    f32x4* __restrict__ dst = dpk + p.dpk_off[l];
    for (int k = blockIdx.x * 256 + threadIdx.x; k < res3; k += gridDim.x * 256) {
        const f32x2 a = src[k];
        const f32x2 b = src[k + 1];
        f32x4 v; v.x = a.x; v.y = a.y; v.z = b.x; v.w = b.y;
        dst[k] = v;
    }
}

// One block = 256 points x 1 level (level = blockIdx.y, slowest dim -> one
// level's table hot per XCD L2).
__global__ __launch_bounds__(256) void hashgrid_level(
    const float* __restrict__ x,
    const float* __restrict__ table,
    const f32x4* __restrict__ dpk,   // tier-B fp32 dense pairs or nullptr
    const u32x4* __restrict__ hq,    // fp16 hashed tables or nullptr
    const u32x4* __restrict__ dq,    // fp16 dense quads or nullptr
    f32x2* __restrict__ dst,
    HGParams p,
    int npoints,
    size_t stride_l,
    size_t stride_n)
{
    __shared__ float sx[768];
    const int tid = threadIdx.x;
    const int base = blockIdx.x << 8;
    const int l = blockIdx.y;

    const int total = npoints * 3;
#pragma unroll
    for (int k = 0; k < 3; ++k) {
        const int li = tid + (k << 8);
        const int gi = base * 3 + li;
        sx[li] = (gi < total) ? x[gi] : 0.0f;
    }
    __syncthreads();

    const int n = base + tid;
    if (n >= npoints) return;

    const float scale = p.scale[l];
    const int   res   = p.res[l];
    const bool  dense = (p.dense[l] != 0);

    const float px = sx[tid * 3 + 0] * scale + 0.5f;
    const float py = sx[tid * 3 + 1] * scale + 0.5f;
    const float pz = sx[tid * 3 + 2] * scale + 0.5f;
    const float fx = floorf(px), fy = floorf(py), fz = floorf(pz);
    const float rx = px - fx,  ry = py - fy,  rz = pz - fz;
    const int ix = (int)fx, iy = (int)fy, iz = (int)fz;

    const f32x2* __restrict__ tbl =
        (const f32x2*)table + (size_t)l * (size_t)HASHMAP;

    const float wx0 = 1.0f - rx, wx1 = rx;
    const float wy_[2] = {1.0f - ry, ry};
    const float wz_[2] = {1.0f - rz, rz};

    float ax = 0.0f, ay = 0.0f;
    float osc = 1.0f;

    if (dense) {
        const int rm = res - 1;
        const int x0 = min(ix, rm);
        const int y0 = min(iy, rm);
        const int z0 = min(iz, rm), z1 = min(iz + 1, rm);
        const int r2 = res * res;
        if (dq && p.dq_off[l] >= 0) {
            // fp16 2x2 xy-quads: one 16B request per z-corner.
            osc = F16UNSCALE;
            const u32x4* __restrict__ dt = dq + p.dq_off[l];
            const int b = x0 + y0 * res;
            const u32x4 qa = dt[b + z0 * r2];
            const u32x4 qb = dt[b + z1 * r2];
            const float wy0 = wy_[0], wy1 = wy_[1];
            float a00x, a00y, a10x, a10y, a01x, a01y, a11x, a11y;
            unpack_h2(qa.x, a00x, a00y);
            unpack_h2(qa.y, a10x, a10y);
            unpack_h2(qa.z, a01x, a01y);
            unpack_h2(qa.w, a11x, a11y);
            const float bax = wy0 * (wx0 * a00x + wx1 * a10x)
                            + wy1 * (wx0 * a01x + wx1 * a11x);
            const float bay = wy0 * (wx0 * a00y + wx1 * a10y)
                            + wy1 * (wx0 * a01y + wx1 * a11y);
            float b00x, b00y, b10x, b10y, b01x, b01y, b11x, b11y;
            unpack_h2(qb.x, b00x, b00y);
            unpack_h2(qb.y, b10x, b10y);
            unpack_h2(qb.z, b01x, b01y);
            unpack_h2(qb.w, b11x, b11y);
            const float bbx = wy0 * (wx0 * b00x + wx1 * b10x)
                            + wy1 * (wx0 * b01x + wx1 * b11x);
            const float bby = wy0 * (wx0 * b00y + wx1 * b10y)
                            + wy1 * (wx0 * b01y + wx1 * b11y);
            ax = wz_[0] * bax + wz_[1] * bbx;
            ay = wz_[0] * bay + wz_[1] * bby;
        } else {
            const int x1 = min(ix + 1, rm);
            const int yy1 = min(iy + 1, rm);
            const int ys[2] = {y0 * res, yy1 * res};
            const int zs[2] = {z0 * r2,  z1 * r2};
            const int d = x1 - x0;  // 0 or 1
            if (dpk && p.dpk_off[l] >= 0) {
                const f32x4* __restrict__ dt = dpk + p.dpk_off[l];
                f32x4 f4[4];
#pragma unroll
                for (int c = 0; c < 4; ++c)
                    f4[c] = dt[x0 + ys[(c >> 1) & 1] + zs[c & 1]];
#pragma unroll
                for (int c = 0; c < 4; ++c) {
                    const f32x2 c0 = f4[c].xy;
                    const f32x2 c1 = d ? f4[c].zw : f4[c].xy;
                    const float wyz = wy_[(c >> 1) & 1] * wz_[c & 1];
                    ax += wyz * (wx0 * c0.x + wx1 * c1.x);
                    ay += wyz * (wx0 * c0.y + wx1 * c1.y);
                }
            } else {
                f32x2 f0[4], f1[4];
#pragma unroll
                for (int c = 0; c < 4; ++c) {
                    const int b = ys[(c >> 1) & 1] + zs[c & 1];
                    f0[c] = tbl[x0 + b];
                    f1[c] = tbl[x1 + b];
                }
#pragma unroll
                for (int c = 0; c < 4; ++c) {
                    const float wyz = wy_[(c >> 1) & 1] * wz_[c & 1];
                    ax += wyz * (wx0 * f0[c].x + wx1 * f1[c].x);
                    ay += wyz * (wx0 * f0[c].y + wx1 * f1[c].y);
                }
            }
        }
    } else {
        const uint32_t ux = (uint32_t)ix;
        const uint32_t hy[2] = {(uint32_t)iy * PRIME_Y, (uint32_t)(iy + 1) * PRIME_Y};
        const uint32_t hz[2] = {(uint32_t)iz * PRIME_Z, (uint32_t)(iz + 1) * PRIME_Z};

        uint32_t H0[4], H1[4];
#pragma unroll
        for (int c = 0; c < 4; ++c) {
            const uint32_t hyz = hy[(c >> 1) & 1] ^ hz[c & 1];
            H0[c] = (ux ^ hyz) & HMASK;
            H1[c] = ((ux + 1u) ^ hyz) & HMASK;
        }

        if (hq && p.hq_off[l] >= 0) {
            // fp16 quads: H0,H1 share a quad unless ix%4==3 (25% of lanes).
            osc = F16UNSCALE;
            const u32x4* __restrict__ ht = hq + p.hq_off[l];
            u32x4 q0[4];
#pragma unroll
            for (int c = 0; c < 4; ++c) q0[c] = ht[H0[c] >> 2];
            const bool straddle = ((ux & 3u) == 3u);
            u32x4 q1[4];
            if (straddle) {
#pragma unroll
                for (int c = 0; c < 4; ++c) q1[c] = ht[H1[c] >> 2];
            }
#pragma unroll
            for (int c = 0; c < 4; ++c) {
                const uint32_t e0 = sel4(q0[c], H0[c] & 3u);
                uint32_t e1;
                if (straddle) e1 = sel4(q1[c], H1[c] & 3u);
                else          e1 = sel4(q0[c], H1[c] & 3u);
                float c0x, c0y, c1x, c1y;
                unpack_h2(e0, c0x, c0y);
                unpack_h2(e1, c1x, c1y);
                const float wyz = wy_[(c >> 1) & 1] * wz_[c & 1];
                ax += wyz * (wx0 * c0x + wx1 * c1x);
                ay += wyz * (wx0 * c0y + wx1 * c1y);
            }
        } else {
            // fp32 pair trick (fallback): 4 dwordx4 + odd lanes 4 dwordx2.
            const f32x4* __restrict__ t4 = (const f32x4*)tbl;
            f32x4 f4[4];
#pragma unroll
            for (int c = 0; c < 4; ++c) f4[c] = t4[H0[c] >> 1];
            f32x2 c1v[4];
            if (ux & 1u) {
#pragma unroll
                for (int c = 0; c < 4; ++c) c1v[c] = tbl[H1[c]];
            } else {
#pragma unroll
                for (int c = 0; c < 4; ++c)
                    c1v[c] = (H0[c] & 1u) ? f4[c].xy : f4[c].zw;
            }
#pragma unroll
            for (int c = 0; c < 4; ++c) {
                const f32x2 c0 = (H0[c] & 1u) ? f4[c].zw : f4[c].xy;
                const float wyz = wy_[(c >> 1) & 1] * wz_[c & 1];
                ax += wyz * (wx0 * c0.x + wx1 * c1v[c].x);
                ay += wyz * (wx0 * c0.y + wx1 * c1v[c].y);
            }
        }
    }

    f32x2 acc; acc.x = ax * osc; acc.y = ay * osc;
    __builtin_nontemporal_store(acc, dst + (size_t)l * stride_l + (size_t)n * stride_n);
}

// Transpose [16][N] f32x2 -> [N][16] f32x2, float4 on both global sides.
__global__ __launch_bounds__(256) void transpose_out(
    const f32x4* __restrict__ ws4,
    f32x4* __restrict__ out4,
    int npoints)
{
    __shared__ f32x2 tile[NLEVELS][130];
    const int tid = threadIdx.x;
    const int base = blockIdx.x << 7;    // 128 points per block
    const int np2 = npoints >> 1;

#pragma unroll
    for (int k = 0; k < 4; ++k) {
        const int flat = tid + (k << 8);
        const int l  = flat >> 6;
        const int pr = flat & 63;
        const int gp = (base >> 1) + pr;
        if (gp < np2) {
            const f32x4 v = __builtin_nontemporal_load(ws4 + (size_t)l * np2 + gp);
            tile[l][2 * pr]     = v.xy;
            tile[l][2 * pr + 1] = v.zw;
        }
    }
    __syncthreads();

#pragma unroll
    for (int k = 0; k < 4; ++k) {
        const int flat = tid + (k << 8);
        const int nl = flat >> 3;
        const int c  = flat & 7;
        const int nn = base + nl;
        if (nn < npoints) {
            const f32x2 a = tile[2 * c][nl];
            const f32x2 b = tile[2 * c + 1][nl];
            f32x4 v; v.x = a.x; v.y = a.y; v.z = b.x; v.w = b.y;
            __builtin_nontemporal_store(v, out4 + (size_t)nn * 8 + c);
        }
    }
}

extern "C" void kernel_launch(void* const* d_in, const int* in_sizes, int n_in,
                              void* d_out, int out_size, void* d_ws, size_t ws_size,
                              hipStream_t stream) {
    const float* x     = (const float*)d_in[0];
    const float* table = (const float*)d_in[1];
    float* out         = (float*)d_out;
    const int npoints  = in_sizes[0] / 3;

    HGParams p;
    const double B = pow(2.0, 7.0 / 15.0);
    int dpk_total = 0;   // f32x4 entries for tier-B dense repack
    int dq_total = 0;    // u32x4 entries for fp16 dense quads
    int hq_total = 0;    // u32x4 entries for fp16 hashed tables
    int max_res3 = 0;
    for (int l = 0; l < NLEVELS; ++l) {
        const double s = 16.0 * pow(B, (double)l) - 1.0;
        p.scale[l] = (float)s;
        const int res = (int)ceil(s) + 1;
        p.res[l] = res;
        const long long r3 = (long long)res * res * res;
        p.dense[l] = (r3 <= (long long)HASHMAP) ? 1 : 0;
        if (p.dense[l]) {
            p.dpk_off[l] = dpk_total;  dpk_total += (int)r3;
            p.dq_off[l]  = dq_total;   dq_total  += (int)r3;
            p.hq_off[l]  = -1;
            if ((int)r3 > max_res3) max_res3 = (int)r3;
        } else {
            p.dpk_off[l] = -1;
            p.dq_off[l]  = -1;
            p.hq_off[l]  = hq_total;   hq_total  += HASHMAP / 4;
        }
    }

    const size_t need_main = (size_t)npoints * NLEVELS * sizeof(f32x2);
    const bool ws_main = (ws_size >= need_main) && ((npoints & 1) == 0);
    const size_t off0 = ws_main ? need_main : 0;

    const size_t hq_bytes = (size_t)hq_total * 16;
    const size_t dq_bytes = (size_t)dq_total * 16;
    const bool tierA = (ws_size >= off0 + hq_bytes + dq_bytes);

    const u32x4* hq = nullptr;
    const u32x4* dq = nullptr;
    const f32x4* dpk = nullptr;

    if (tierA) {
        uint32_t* hqw = (uint32_t*)((char*)d_ws + off0);
        u32x4*    dqt = (u32x4*)((char*)d_ws + off0 + hq_bytes);
        hq = (const u32x4*)hqw;
        dq = dqt;
        {
            const dim3 gr(1024, NLEVELS);
            repack_hashed_f16<<<gr, 256, 0, stream>>>(
                (const f32x4*)table, hqw, p);
        }
        {
            const dim3 gr((max_res3 + 255) / 256, NLEVELS);
            repack_dense_f16<<<gr, 256, 0, stream>>>(
                (const f32x2*)table, dqt, p);
        }
    } else {
        // tier B: fp32 dense pair repack only
        for (int l = 0; l < NLEVELS; ++l) { p.hq_off[l] = -1; p.dq_off[l] = -1; }
        const size_t need_dpk = (size_t)dpk_total * sizeof(f32x4);
        const bool use_dpk = (ws_size >= off0 + need_dpk) && dpk_total > 0;
        if (use_dpk) {
            f32x4* dpkw = (f32x4*)((char*)d_ws + off0);
            dpk = dpkw;
            const dim3 gr((max_res3 + 255) / 256, NLEVELS);
            repack_dense_k<<<gr, 256, 0, stream>>>((const f32x2*)table, dpkw, p);
        } else {
            for (int l = 0; l < NLEVELS; ++l) p.dpk_off[l] = -1;
        }
    }

    const dim3 g1((npoints + 255) / 256, NLEVELS);
    if (ws_main) {
        hashgrid_level<<<g1, 256, 0, stream>>>(
            x, table, dpk, hq, dq, (f32x2*)d_ws, p, npoints,
            (size_t)npoints, (size_t)1);
        const int nb2 = (npoints + 127) / 128;
        transpose_out<<<nb2, 256, 0, stream>>>(
            (const f32x4*)d_ws, (f32x4*)out, npoints);
    } else {
        hashgrid_level<<<g1, 256, 0, stream>>>(
            x, table, dpk, hq, dq, (f32x2*)out, p, npoints,
            (size_t)1, (size_t)NLEVELS);
    }
}